// Round 1
// 917.025 us; speedup vs baseline: 1.3220x; 1.3220x over previous
//
#include <hip/hip_runtime.h>
#include <hip/hip_bf16.h>
#include <math.h>
#include <float.h>

#define NUM_B 2
#define SEQ_T 2048
#define DIM_D 1024
#define NH 16
#define DH 64
#define KDIM 1024
#define KSEL 8

// attention candidate scheme
#define CAP 32
#define MFMA_MARGIN 0.06f

typedef __attribute__((ext_vector_type(8))) short bf16x8v;   // 8 bf16 (4 VGPR)
typedef __attribute__((ext_vector_type(4))) float f32x4v;    // MFMA acc

__device__ __forceinline__ float bf2f(unsigned int u) {
  union { unsigned int i; float f; } v; v.i = u << 16; return v.f;
}

__device__ __forceinline__ short f2bs(float f) {
  __hip_bfloat16 h = __float2bfloat16(f);
  return *(short*)&h;
}

// swizzled ushort offset of (key in tile, dim) inside a 128x64 bf16 K tile.
// byte = ((key<<7) | (d<<1)) ^ ((key&7)<<4)  ->  ushort = ((key<<6)|d) ^ ((key&7)<<3)
// Q,K projection (cols 0..2047 of qkv): fp64 accumulation, BIT-IDENTICAL to
// the passing path — top-k selection depends on these exact bits.
// Additionally emits kbf: bf16 K image, 16 tiles/bh of 128key x 64dim,
// XOR-swizzled so attn's LDS staging is a linear copy.
__global__ __launch_bounds__(256) void gemm_qk(
    const float* __restrict__ A, const float* __restrict__ Bm,
    float* __restrict__ qbuf, float* __restrict__ kbuf,
    unsigned short* __restrict__ kbf) {
  __shared__ __align__(16) float As[32][64];
  __shared__ __align__(16) float Bs[32][64];
  const int tid = threadIdx.x;
  const int row0 = blockIdx.y * 64;
  const int col0 = blockIdx.x * 64;
  const int lrow = tid >> 2;
  const int lk = (tid & 3) << 3;
  const int tx = tid & 15, ty = tid >> 4;
  const float* ap = A + (size_t)(row0 + lrow) * KDIM + lk;
  const float* bp = Bm + (size_t)(col0 + lrow) * KDIM + lk;
  double c[4][4] = {{0.0, 0.0, 0.0, 0.0}};
  for (int k0 = 0; k0 < KDIM; k0 += 32) {
    const float4 a0 = *(const float4*)(ap + k0);
    const float4 a1 = *(const float4*)(ap + k0 + 4);
    const float4 b0 = *(const float4*)(bp + k0);
    const float4 b1 = *(const float4*)(bp + k0 + 4);
    float* as = &As[lk][lrow];
    float* bs = &Bs[lk][lrow];
    as[0 * 64] = a0.x; as[1 * 64] = a0.y; as[2 * 64] = a0.z; as[3 * 64] = a0.w;
    as[4 * 64] = a1.x; as[5 * 64] = a1.y; as[6 * 64] = a1.z; as[7 * 64] = a1.w;
    bs[0 * 64] = b0.x; bs[1 * 64] = b0.y; bs[2 * 64] = b0.z; bs[3 * 64] = b0.w;
    bs[4 * 64] = b1.x; bs[5 * 64] = b1.y; bs[6 * 64] = b1.z; bs[7 * 64] = b1.w;
    __syncthreads();
#pragma unroll
    for (int kk = 0; kk < 32; ++kk) {
      const float4 a = *(const float4*)&As[kk][ty << 2];
      const float4 b = *(const float4*)&Bs[kk][tx << 2];
      const double ax = a.x, ay = a.y, az = a.z, aw = a.w;
      const double bx = b.x, by = b.y, bz = b.z, bw = b.w;
      c[0][0] = fma(ax, bx, c[0][0]);
      c[0][1] = fma(ax, by, c[0][1]);
      c[0][2] = fma(ax, bz, c[0][2]);
      c[0][3] = fma(ax, bw, c[0][3]);
      c[1][0] = fma(ay, bx, c[1][0]);
      c[1][1] = fma(ay, by, c[1][1]);
      c[1][2] = fma(ay, bz, c[1][2]);
      c[1][3] = fma(ay, bw, c[1][3]);
      c[2][0] = fma(az, bx, c[2][0]);
      c[2][1] = fma(az, by, c[2][1]);
      c[2][2] = fma(az, bz, c[2][2]);
      c[2][3] = fma(az, bw, c[2][3]);
      c[3][0] = fma(aw, bx, c[3][0]);
      c[3][1] = fma(aw, by, c[3][1]);
      c[3][2] = fma(aw, bz, c[3][2]);
      c[3][3] = fma(aw, bw, c[3][3]);
    }
    __syncthreads();
  }
  const int qi = col0 >> 10;            // 0=q 1=k
  const int head = (col0 & 1023) >> 6;
  const int bb = row0 >> 11;
  const int t0 = row0 & 2047;
  const size_t base = (size_t)(bb * NH + head) * SEQ_T * DH;
  float* dst = ((qi == 0) ? qbuf : kbuf) + base;
#pragma unroll
  for (int i = 0; i < 4; ++i)
#pragma unroll
    for (int j = 0; j < 4; ++j)
      dst[(size_t)(t0 + ty * 4 + i) * DH + (tx * 4 + j)] = (float)c[i][j];
  if (qi == 1) {
    unsigned short* kb = kbf + ((size_t)(bb * NH + head) << 17);  // 16*8192
#pragma unroll
    for (int i = 0; i < 4; ++i)
#pragma unroll
      for (int j = 0; j < 4; ++j) {
        const int t = t0 + ty * 4 + i;
        const int d = tx * 4 + j;
        const int key = t & 127;
        const int off = (((t >> 7) << 13) | (key << 6) | d) ^ ((key & 7) << 3);
        __hip_bfloat16 hb = __float2bfloat16((float)c[i][j]);
        kb[off] = *(unsigned short*)&hb;
      }
  }
}

// V projection (cols 2048..3071): fp32 accumulate (V feeds softmax*V and is
// bf16-rounded). Bm passed pre-offset to wqkv + 2048*KDIM.
__global__ __launch_bounds__(256) void gemm_v(
    const float* __restrict__ A, const float* __restrict__ Bm,
    unsigned short* __restrict__ vbuf) {
  __shared__ __align__(16) float As[32][64];
  __shared__ __align__(16) float Bs[32][64];
  const int tid = threadIdx.x;
  const int row0 = blockIdx.y * 64;
  const int col0 = blockIdx.x * 64;
  const int lrow = tid >> 2;
  const int lk = (tid & 3) << 3;
  const int tx = tid & 15, ty = tid >> 4;
  const float* ap = A + (size_t)(row0 + lrow) * KDIM + lk;
  const float* bp = Bm + (size_t)(col0 + lrow) * KDIM + lk;
  float c[4][4] = {{0.f, 0.f, 0.f, 0.f}};
  for (int k0 = 0; k0 < KDIM; k0 += 32) {
    const float4 a0 = *(const float4*)(ap + k0);
    const float4 a1 = *(const float4*)(ap + k0 + 4);
    const float4 b0 = *(const float4*)(bp + k0);
    const float4 b1 = *(const float4*)(bp + k0 + 4);
    float* as = &As[lk][lrow];
    float* bs = &Bs[lk][lrow];
    as[0 * 64] = a0.x; as[1 * 64] = a0.y; as[2 * 64] = a0.z; as[3 * 64] = a0.w;
    as[4 * 64] = a1.x; as[5 * 64] = a1.y; as[6 * 64] = a1.z; as[7 * 64] = a1.w;
    bs[0 * 64] = b0.x; bs[1 * 64] = b0.y; bs[2 * 64] = b0.z; bs[3 * 64] = b0.w;
    bs[4 * 64] = b1.x; bs[5 * 64] = b1.y; bs[6 * 64] = b1.z; bs[7 * 64] = b1.w;
    __syncthreads();
#pragma unroll
    for (int kk = 0; kk < 32; ++kk) {
      const float4 a = *(const float4*)&As[kk][ty << 2];
      const float4 b = *(const float4*)&Bs[kk][tx << 2];
      c[0][0] = fmaf(a.x, b.x, c[0][0]);
      c[0][1] = fmaf(a.x, b.y, c[0][1]);
      c[0][2] = fmaf(a.x, b.z, c[0][2]);
      c[0][3] = fmaf(a.x, b.w, c[0][3]);
      c[1][0] = fmaf(a.y, b.x, c[1][0]);
      c[1][1] = fmaf(a.y, b.y, c[1][1]);
      c[1][2] = fmaf(a.y, b.z, c[1][2]);
      c[1][3] = fmaf(a.y, b.w, c[1][3]);
      c[2][0] = fmaf(a.z, b.x, c[2][0]);
      c[2][1] = fmaf(a.z, b.y, c[2][1]);
      c[2][2] = fmaf(a.z, b.z, c[2][2]);
      c[2][3] = fmaf(a.z, b.w, c[2][3]);
      c[3][0] = fmaf(a.w, b.x, c[3][0]);
      c[3][1] = fmaf(a.w, b.y, c[3][1]);
      c[3][2] = fmaf(a.w, b.z, c[3][2]);
      c[3][3] = fmaf(a.w, b.w, c[3][3]);
    }
    __syncthreads();
  }
  const int head = col0 >> 6;  // col0 in 0..1023 here
  const int bb = row0 >> 11;
  const int t0 = row0 & 2047;
  unsigned short* dst = vbuf + (size_t)(bb * NH + head) * SEQ_T * DH;
#pragma unroll
  for (int i = 0; i < 4; ++i)
#pragma unroll
    for (int j = 0; j < 4; ++j) {
      __hip_bfloat16 h = __float2bfloat16(c[i][j]);
      dst[(size_t)(t0 + ty * 4 + i) * DH + (tx * 4 + j)] = *(unsigned short*)&h;
    }
}

// Attention, MFMA candidate-filter scheme.
// Block = 4 waves = 64 q-rows (16 rows/wave). Pass 1: bf16 MFMA scores
// (16x16x32), per-lane top-8 per C-slot + 16-lane bitonic merge -> per-row
// approx top-8 threshold. Pass 2: identical MFMA re-scan, push keys with
// s >= thr - MARGIN into per-row LDS candidate lists (margin 0.06 covers
// bf16 score error <= ~0.01 with huge slack; exact selection is re-derived
// below so approx errors cannot change the output beyond candidate choice).
// Phase 3: exact fp64 rescore per candidate, fp64 top-8 threshold (ties
// kept), sparse softmax*V -> value-identical to the fp64-exact path.
__global__ __launch_bounds__(256) void attn_topk(
    const float* __restrict__ q, const float* __restrict__ kmat,
    const unsigned short* __restrict__ kbf,
    const unsigned short* __restrict__ v, unsigned short* __restrict__ ctx) {
  __shared__ __align__(16) unsigned short kt[128 * 64];  // 16KB swizzled tile
  __shared__ double cs64[64][CAP];                       // 16KB exact scores
  __shared__ short ckey[64][CAP];                        // 4KB candidate keys
  __shared__ int ccnt[64];
  __shared__ double rthr[64];
  __shared__ float rmx[64];

  const int tid = threadIdx.x;
  const int lane = tid & 63;
  const int w = tid >> 6;
  const int bh = blockIdx.x & 31;
  const int t0 = (blockIdx.x >> 5) << 6;
  const size_t kbase = (size_t)bh * SEQ_T * DH;
  const int wrow0 = t0 + (w << 4);
  const int kA = (lane >> 4) << 3;                 // A/B-frag k-run offset
  const int rbase = wrow0 + ((lane >> 4) << 2);    // C row of acc[0]

  // Q fragment (A operand): row = lane&15, k = 8*(lane>>4)+j (+32 for half 1)
  bf16x8v qa0, qa1;
  {
    const float* qr = q + kbase + (size_t)(wrow0 + (lane & 15)) * DH;
    const float4 x0 = *(const float4*)(qr + kA);
    const float4 x1 = *(const float4*)(qr + kA + 4);
    const float4 y0 = *(const float4*)(qr + 32 + kA);
    const float4 y1 = *(const float4*)(qr + 32 + kA + 4);
    qa0[0] = f2bs(x0.x); qa0[1] = f2bs(x0.y);
    qa0[2] = f2bs(x0.z); qa0[3] = f2bs(x0.w);
    qa0[4] = f2bs(x1.x); qa0[5] = f2bs(x1.y);
    qa0[6] = f2bs(x1.z); qa0[7] = f2bs(x1.w);
    qa1[0] = f2bs(y0.x); qa1[1] = f2bs(y0.y);
    qa1[2] = f2bs(y0.z); qa1[3] = f2bs(y0.w);
    qa1[4] = f2bs(y1.x); qa1[5] = f2bs(y1.y);
    qa1[6] = f2bs(y1.z); qa1[7] = f2bs(y1.w);
  }

  const uint4* ksrc = (const uint4*)(kbf + ((size_t)bh << 17));
  const int nt = (t0 >> 7) + 1;       // tiles covering keys 0..t0+63
  const int wmax = wrow0 + 15;

  float tq[4][8];
#pragma unroll
  for (int j = 0; j < 4; ++j)
#pragma unroll
    for (int m = 0; m < 8; ++m) tq[j][m] = -FLT_MAX;

  // ---- pass 1: MFMA scores + per-lane top-8 per slot ----
  for (int T = 0; T < nt; ++T) {
    if (T) __syncthreads();
    {
      const uint4* st = ksrc + (size_t)T * 1024;
      uint4* dv = (uint4*)kt;
#pragma unroll
      for (int i = 0; i < 4; ++i) dv[i * 256 + tid] = st[i * 256 + tid];
    }
    __syncthreads();
    const int glim0 = (wmax - (T << 7)) >> 4;
    const int glim = glim0 > 7 ? 7 : glim0;
    for (int gt = 0; gt <= glim; ++gt) {
      const int kk = (gt << 4) + (lane & 15);
      const int key = (T << 7) + kk;
      const int b0 = ((kk << 7) | (kA << 1)) ^ ((kk & 7) << 4);
      const int b1 = ((kk << 7) | ((32 + kA) << 1)) ^ ((kk & 7) << 4);
      const bf16x8v kb0 = *(const bf16x8v*)((const char*)kt + b0);
      const bf16x8v kb1 = *(const bf16x8v*)((const char*)kt + b1);
      f32x4v acc = {0.f, 0.f, 0.f, 0.f};
      acc = __builtin_amdgcn_mfma_f32_16x16x32_bf16(qa0, kb0, acc, 0, 0, 0);
      acc = __builtin_amdgcn_mfma_f32_16x16x32_bf16(qa1, kb1, acc, 0, 0, 0);
#pragma unroll
      for (int j = 0; j < 4; ++j) {
        float sc = acc[j] * 0.125f;
        sc = (key <= rbase + j) ? sc : -FLT_MAX;
        if (sc > tq[j][7]) {
          float s = sc;
#pragma unroll
          for (int m = 0; m < 8; ++m) {
            const float hi = fmaxf(tq[j][m], s);
            s = fminf(tq[j][m], s);
            tq[j][m] = hi;
          }
        }
      }
    }
  }

  // ---- merge per slot across the 16-lane group (4 bitonic rounds) ----
#pragma unroll
  for (int j = 0; j < 4; ++j) {
#pragma unroll
    for (int xm = 1; xm < 16; xm <<= 1) {
      float m[8];
#pragma unroll
      for (int i = 0; i < 8; ++i) {
        const float pb = __shfl_xor(tq[j][7 - i], xm);
        m[i] = fmaxf(tq[j][i], pb);
      }
#pragma unroll
      for (int d = 4; d >= 1; d >>= 1)
#pragma unroll
        for (int i = 0; i < 8; ++i)
          if ((i & d) == 0 && (i | d) < 8) {
            const float hi = fmaxf(m[i], m[i | d]);
            const float lo = fminf(m[i], m[i | d]);
            m[i] = hi;
            m[i | d] = lo;
          }
#pragma unroll
      for (int i = 0; i < 8; ++i) tq[j][i] = m[i];
    }
  }
  float thrj[4];
#pragma unroll
  for (int j = 0; j < 4; ++j) {
    const int kf = (rbase + j + 1 < KSEL) ? (rbase + j + 1) : KSEL;
    float th = tq[j][7];
#pragma unroll
    for (int m = 0; m < 8; ++m)
      if (m == kf - 1) th = tq[j][m];
    thrj[j] = th - MFMA_MARGIN;
  }

  if (tid < 64) ccnt[tid] = 0;
  __syncthreads();

  // ---- pass 2: identical MFMA re-scan, collect candidates ----
  for (int T = 0; T < nt; ++T) {
    if (T) __syncthreads();
    {
      const uint4* st = ksrc + (size_t)T * 1024;
      uint4* dv = (uint4*)kt;
#pragma unroll
      for (int i = 0; i < 4; ++i) dv[i * 256 + tid] = st[i * 256 + tid];
    }
    __syncthreads();
    const int glim0 = (wmax - (T << 7)) >> 4;
    const int glim = glim0 > 7 ? 7 : glim0;
    for (int gt = 0; gt <= glim; ++gt) {
      const int kk = (gt << 4) + (lane & 15);
      const int key = (T << 7) + kk;
      const int b0 = ((kk << 7) | (kA << 1)) ^ ((kk & 7) << 4);
      const int b1 = ((kk << 7) | ((32 + kA) << 1)) ^ ((kk & 7) << 4);
      const bf16x8v kb0 = *(const bf16x8v*)((const char*)kt + b0);
      const bf16x8v kb1 = *(const bf16x8v*)((const char*)kt + b1);
      f32x4v acc = {0.f, 0.f, 0.f, 0.f};
      acc = __builtin_amdgcn_mfma_f32_16x16x32_bf16(qa0, kb0, acc, 0, 0, 0);
      acc = __builtin_amdgcn_mfma_f32_16x16x32_bf16(qa1, kb1, acc, 0, 0, 0);
#pragma unroll
      for (int j = 0; j < 4; ++j) {
        const float sc = acc[j] * 0.125f;
        if (key <= rbase + j && sc >= thrj[j]) {
          const int rl = (w << 4) + ((lane >> 4) << 2) + j;
          const int p = atomicAdd(&ccnt[rl], 1);
          if (p < CAP) ckey[rl][p] = (short)key;
        }
      }
    }
  }

  // ---- phase 3A: exact fp64 rescore, lane-per-candidate, 2 rows/iter ----
  const int lid = lane & 31;
  for (int rp = 0; rp < 8; ++rp) {
    const int rl = (w << 4) + (rp << 1) + (lane >> 5);
    const int ncc = ccnt[rl] < CAP ? ccnt[rl] : CAP;
    if (lid < ncc) {
      const int key = ckey[rl][lid];
      const float* qr = q + kbase + (size_t)(t0 + rl) * DH;
      const float* kr = kmat + kbase + (size_t)key * DH;
      double s = 0.0;
#pragma unroll
      for (int d4 = 0; d4 < 16; ++d4) {
        const float4 qq = *(const float4*)(qr + (d4 << 2));
        const float4 kq = *(const float4*)(kr + (d4 << 2));
        s = fma((double)qq.x, (double)kq.x, s);
        s = fma((double)qq.y, (double)kq.y, s);
        s = fma((double)qq.z, (double)kq.z, s);
        s = fma((double)qq.w, (double)kq.w, s);
      }
      cs64[rl][lid] = s * 0.125;
    }
  }
  __syncthreads();

  // ---- phase 3B: per-row fp64 top-8 + threshold (row per lane) ----
  if (lane < 16) {
    const int rl = (w << 4) + lane;
    const int trow = t0 + rl;
    const int ncc = ccnt[rl] < CAP ? ccnt[rl] : CAP;
    double a64[8];
#pragma unroll
    for (int j = 0; j < 8; ++j) a64[j] = -DBL_MAX;
    for (int l = 0; l < ncc; ++l) {
      double sv = cs64[rl][l];
#pragma unroll
      for (int j = 0; j < 8; ++j) {
        const double hi = fmax(a64[j], sv);
        sv = fmin(a64[j], sv);
        a64[j] = hi;
      }
    }
    const int kf = (trow + 1 < KSEL) ? (trow + 1) : KSEL;
    double th = a64[7];
#pragma unroll
    for (int j = 0; j < 8; ++j)
      if (j == kf - 1) th = a64[j];
    rthr[rl] = th;
    rmx[rl] = (float)a64[0];
  }
  __syncthreads();

  // ---- phase 3C: sparse softmax * V (keep = s64 >= thr64, ties kept) ----
  for (int r = 0; r < 16; ++r) {
    const int rl = (w << 4) + r;
    const int ncc = ccnt[rl] < CAP ? ccnt[rl] : CAP;
    const double th = rthr[rl];
    const float mxf = rmx[rl];
    float accv = 0.f, Z = 0.f;
    for (int l = 0; l < ncc; ++l) {
      const double s = cs64[rl][l];
      if (s >= th) {
        const float wg = expf((float)s - mxf);
        Z += wg;
        accv = fmaf(
            wg,
            bf2f((unsigned int)v[kbase + (size_t)ckey[rl][l] * DH + lane]),
            accv);
      }
    }
    const int trow = t0 + rl;
    __hip_bfloat16 h = __float2bfloat16(accv / Z);
    ctx[((size_t)(bh >> 4) * SEQ_T + trow) * DIM_D + (bh & 15) * DH + lane] =
        *(unsigned short*)&h;
  }
}

// Output projection: out[4096 x 1024] = ctx(bf16) * wout^T(fp32), fp32 out.
__global__ __launch_bounds__(256) void gemm_out(
    const unsigned short* __restrict__ A, const float* __restrict__ Bm,
    float* __restrict__ obuf) {
  __shared__ __align__(16) float As[32][64];
  __shared__ __align__(16) float Bs[32][64];
  const int tid = threadIdx.x;
  const int row0 = blockIdx.y * 64;
  const int col0 = blockIdx.x * 64;
  const int lrow = tid >> 2;
  const int lk = (tid & 3) << 3;
  const int tx = tid & 15, ty = tid >> 4;
  const unsigned short* ap = A + (size_t)(row0 + lrow) * KDIM + lk;
  const float* bp = Bm + (size_t)(col0 + lrow) * KDIM + lk;
  float c[4][4] = {{0.f, 0.f, 0.f, 0.f}};
  for (int k0 = 0; k0 < KDIM; k0 += 32) {
    const uint4 u = *(const uint4*)(ap + k0);
    const float4 b0 = *(const float4*)(bp + k0);
    const float4 b1 = *(const float4*)(bp + k0 + 4);
    float* as = &As[lk][lrow];
    float* bs = &Bs[lk][lrow];
    as[0 * 64] = bf2f(u.x & 0xffffu); as[1 * 64] = bf2f(u.x >> 16);
    as[2 * 64] = bf2f(u.y & 0xffffu); as[3 * 64] = bf2f(u.y >> 16);
    as[4 * 64] = bf2f(u.z & 0xffffu); as[5 * 64] = bf2f(u.z >> 16);
    as[6 * 64] = bf2f(u.w & 0xffffu); as[7 * 64] = bf2f(u.w >> 16);
    bs[0 * 64] = b0.x; bs[1 * 64] = b0.y; bs[2 * 64] = b0.z; bs[3 * 64] = b0.w;
    bs[4 * 64] = b1.x; bs[5 * 64] = b1.y; bs[6 * 64] = b1.z; bs[7 * 64] = b1.w;
    __syncthreads();
#pragma unroll
    for (int kk = 0; kk < 32; ++kk) {
      const float4 a = *(const float4*)&As[kk][ty << 2];
      const float4 b = *(const float4*)&Bs[kk][tx << 2];
      c[0][0] = fmaf(a.x, b.x, c[0][0]);
      c[0][1] = fmaf(a.x, b.y, c[0][1]);
      c[0][2] = fmaf(a.x, b.z, c[0][2]);
      c[0][3] = fmaf(a.x, b.w, c[0][3]);
      c[1][0] = fmaf(a.y, b.x, c[1][0]);
      c[1][1] = fmaf(a.y, b.y, c[1][1]);
      c[1][2] = fmaf(a.y, b.z, c[1][2]);
      c[1][3] = fmaf(a.y, b.w, c[1][3]);
      c[2][0] = fmaf(a.z, b.x, c[2][0]);
      c[2][1] = fmaf(a.z, b.y, c[2][1]);
      c[2][2] = fmaf(a.z, b.z, c[2][2]);
      c[2][3] = fmaf(a.z, b.w, c[2][3]);
      c[3][0] = fmaf(a.w, b.x, c[3][0]);
      c[3][1] = fmaf(a.w, b.y, c[3][1]);
      c[3][2] = fmaf(a.w, b.z, c[3][2]);
      c[3][3] = fmaf(a.w, b.w, c[3][3]);
    }
    __syncthreads();
  }
#pragma unroll
  for (int i = 0; i < 4; ++i)
#pragma unroll
    for (int j = 0; j < 4; ++j)
      obuf[(size_t)(row0 + ty * 4 + i) * DIM_D + (col0 + tx * 4 + j)] = c[i][j];
}

extern "C" void kernel_launch(void* const* d_in, const int* in_sizes, int n_in,
                              void* d_out, int out_size, void* d_ws,
                              size_t ws_size, hipStream_t stream) {
  (void)out_size; (void)ws_size;
  const float* x = (const float*)d_in[0];
  const float* wqkv = (const float*)d_in[1];
  const float* wout = (const float*)d_in[2];
  for (int i = 0; i < n_in; ++i) {
    if (in_sizes[i] == NUM_B * SEQ_T * DIM_D) x = (const float*)d_in[i];
    else if (in_sizes[i] == 3 * DIM_D * DIM_D) wqkv = (const float*)d_in[i];
    else if (in_sizes[i] == DIM_D * DIM_D) wout = (const float*)d_in[i];
  }
  float* out = (float*)d_out;

  const size_t qkv_elems = (size_t)NUM_B * NH * SEQ_T * DH;   // 4.19M
  float* qbuf = (float*)d_ws;
  float* kbuf = qbuf + qkv_elems;
  unsigned short* vbuf = (unsigned short*)(kbuf + qkv_elems);
  unsigned short* ctxb = vbuf + qkv_elems;
  unsigned short* kbf = ctxb + (size_t)NUM_B * SEQ_T * DIM_D;  // bf16 K tiles

  gemm_qk<<<dim3(2 * DIM_D / 64, NUM_B * SEQ_T / 64), 256, 0, stream>>>(
      x, wqkv, qbuf, kbuf, kbf);
  gemm_v<<<dim3(DIM_D / 64, NUM_B * SEQ_T / 64), 256, 0, stream>>>(
      x, wqkv + (size_t)2 * DIM_D * KDIM, vbuf);
  attn_topk<<<dim3(NUM_B * NH * (SEQ_T / 64)), 256, 0, stream>>>(
      qbuf, kbuf, kbf, vbuf, ctxb);
  gemm_out<<<dim3(DIM_D / 64, NUM_B * SEQ_T / 64), 256, 0, stream>>>(
      ctxb, wout, out);
}

// Round 3
// 790.385 us; speedup vs baseline: 1.5339x; 1.1602x over previous
//
#include <hip/hip_runtime.h>
#include <hip/hip_bf16.h>
#include <math.h>
#include <float.h>

#define NUM_B 2
#define SEQ_T 2048
#define DIM_D 1024
#define NH 16
#define DH 64
#define KDIM 1024
#define KSEL 8

// attention candidate scheme
#define CAP 32
#define MFMA_MARGIN 0.06f

typedef __attribute__((ext_vector_type(8))) short bf16x8v;   // 8 bf16 (4 VGPR)
typedef __attribute__((ext_vector_type(4))) float f32x4v;    // MFMA acc
typedef __attribute__((ext_vector_type(4))) double f64x4v;   // f64 MFMA acc

__device__ __forceinline__ float bf2f(unsigned int u) {
  union { unsigned int i; float f; } v; v.i = u << 16; return v.f;
}

__device__ __forceinline__ short f2bs(float f) {
  __hip_bfloat16 h = __float2bfloat16(f);
  return *(short*)&h;
}

// Q,K projection (cols 0..2047 of qkv): fp64 accumulation via
// v_mfma_f64_16x16x4 (matrix pipe). Same fp64 products as the serial chain
// (order differs by <=1 ulp, ~1e-16 rel — far below the ~1e-5 near-tie
// scale), so selection downstream is unchanged.
// The C/D fragment layout is decoded AT RUNTIME with two probe MFMAs
// (A=rowidx,B=1 -> 4*row ; A=1,B=colidx -> 4*col), so the epilogue is
// correct under any (blocked/interleaved/transposed) layout — this was the
// round-2 failure mode.
// Also emits kbf: bf16 K image, 16 tiles/bh of 128key x 64dim, XOR-swizzled
// so attn's LDS staging is a linear copy.
__global__ __launch_bounds__(256) void gemm_qk(
    const float* __restrict__ A, const float* __restrict__ Bm,
    float* __restrict__ qbuf, float* __restrict__ kbuf,
    unsigned short* __restrict__ kbf) {
  __shared__ __align__(16) float As[64][36];   // row-major, +4 pad
  __shared__ __align__(16) float Bs[64][36];
  const int tid = threadIdx.x;
  const int lane = tid & 63;
  const int w = tid >> 6;
  const int row0 = blockIdx.y * 64;
  const int col0 = blockIdx.x * 64;
  // staging: thread loads 8 consecutive k of one row (A and B)
  const int lrow = tid >> 2;        // 0..63
  const int lk = (tid & 3) << 3;    // 0,8,16,24
  const float* ap = A + (size_t)(row0 + lrow) * KDIM + lk;
  const float* bp = Bm + (size_t)(col0 + lrow) * KDIM + lk;
  // wave tile: 32x32 = 2x2 MFMA subtiles
  const int wr = (w >> 1) << 5;     // 0 or 32 (row offset)
  const int wc = (w & 1) << 5;      // 0 or 32 (col offset)
  const int li = lane & 15;         // A row / B col within subtile
  const int lk4 = lane >> 4;        // k within 4-step (A/B frag)

  // ---- C/D layout probe: decode (row,col) of each acc slot at runtime ----
  int rowof[4], colof[4];
  {
    f64x4v pr = {0.0, 0.0, 0.0, 0.0};
    f64x4v pc = {0.0, 0.0, 0.0, 0.0};
    const double vidx = (double)li;
    pr = __builtin_amdgcn_mfma_f64_16x16x4f64(vidx, 1.0, pr, 0, 0, 0);
    pc = __builtin_amdgcn_mfma_f64_16x16x4f64(1.0, vidx, pc, 0, 0, 0);
#pragma unroll
    for (int vj = 0; vj < 4; ++vj) {
      rowof[vj] = (int)(pr[vj] * 0.25 + 0.5);
      colof[vj] = (int)(pc[vj] * 0.25 + 0.5);
    }
  }

  f64x4v acc[2][2];
#pragma unroll
  for (int m = 0; m < 2; ++m)
#pragma unroll
    for (int n = 0; n < 2; ++n)
      acc[m][n] = (f64x4v){0.0, 0.0, 0.0, 0.0};

  for (int k0 = 0; k0 < KDIM; k0 += 32) {
    const float4 a0 = *(const float4*)(ap + k0);
    const float4 a1 = *(const float4*)(ap + k0 + 4);
    const float4 b0 = *(const float4*)(bp + k0);
    const float4 b1 = *(const float4*)(bp + k0 + 4);
    *(float4*)&As[lrow][lk] = a0;
    *(float4*)&As[lrow][lk + 4] = a1;
    *(float4*)&Bs[lrow][lk] = b0;
    *(float4*)&Bs[lrow][lk + 4] = b1;
    __syncthreads();
#pragma unroll
    for (int ks = 0; ks < 32; ks += 4) {
      const int kk = ks + lk4;
      const double af0 = (double)As[wr + li][kk];
      const double af1 = (double)As[wr + 16 + li][kk];
      const double bf0 = (double)Bs[wc + li][kk];
      const double bf1 = (double)Bs[wc + 16 + li][kk];
      acc[0][0] = __builtin_amdgcn_mfma_f64_16x16x4f64(af0, bf0, acc[0][0], 0, 0, 0);
      acc[0][1] = __builtin_amdgcn_mfma_f64_16x16x4f64(af0, bf1, acc[0][1], 0, 0, 0);
      acc[1][0] = __builtin_amdgcn_mfma_f64_16x16x4f64(af1, bf0, acc[1][0], 0, 0, 0);
      acc[1][1] = __builtin_amdgcn_mfma_f64_16x16x4f64(af1, bf1, acc[1][1], 0, 0, 0);
    }
    __syncthreads();
  }

  const int qi = col0 >> 10;            // 0=q 1=k
  const int head = (col0 & 1023) >> 6;
  const int bb = row0 >> 11;
  const int t0 = row0 & 2047;
  const size_t base = (size_t)(bb * NH + head) * SEQ_T * DH;
  float* dst = ((qi == 0) ? qbuf : kbuf) + base;
  unsigned short* kb = kbf + ((size_t)(bb * NH + head) << 17);  // 16*8192
#pragma unroll
  for (int m = 0; m < 2; ++m)
#pragma unroll
    for (int n = 0; n < 2; ++n)
#pragma unroll
      for (int vj = 0; vj < 4; ++vj) {
        const int r = wr + 16 * m + rowof[vj];      // row in tile (0..63)
        const int dcol = wc + 16 * n + colof[vj];   // col in tile (0..63)
        const int t = t0 + r;
        const float fv = (float)acc[m][n][vj];
        dst[(size_t)t * DH + dcol] = fv;
        if (qi == 1) {
          const int key = t & 127;
          const int off =
              (((t >> 7) << 13) | (key << 6) | dcol) ^ ((key & 7) << 3);
          __hip_bfloat16 hb = __float2bfloat16(fv);
          kb[off] = *(unsigned short*)&hb;
        }
      }
}

// V projection (cols 2048..3071): fp32 accumulate (V feeds softmax*V and is
// bf16-rounded). Bm passed pre-offset to wqkv + 2048*KDIM.
__global__ __launch_bounds__(256) void gemm_v(
    const float* __restrict__ A, const float* __restrict__ Bm,
    unsigned short* __restrict__ vbuf) {
  __shared__ __align__(16) float As[32][64];
  __shared__ __align__(16) float Bs[32][64];
  const int tid = threadIdx.x;
  const int row0 = blockIdx.y * 64;
  const int col0 = blockIdx.x * 64;
  const int lrow = tid >> 2;
  const int lk = (tid & 3) << 3;
  const int tx = tid & 15, ty = tid >> 4;
  const float* ap = A + (size_t)(row0 + lrow) * KDIM + lk;
  const float* bp = Bm + (size_t)(col0 + lrow) * KDIM + lk;
  float c[4][4] = {{0.f, 0.f, 0.f, 0.f}};
  for (int k0 = 0; k0 < KDIM; k0 += 32) {
    const float4 a0 = *(const float4*)(ap + k0);
    const float4 a1 = *(const float4*)(ap + k0 + 4);
    const float4 b0 = *(const float4*)(bp + k0);
    const float4 b1 = *(const float4*)(bp + k0 + 4);
    float* as = &As[lk][lrow];
    float* bs = &Bs[lk][lrow];
    as[0 * 64] = a0.x; as[1 * 64] = a0.y; as[2 * 64] = a0.z; as[3 * 64] = a0.w;
    as[4 * 64] = a1.x; as[5 * 64] = a1.y; as[6 * 64] = a1.z; as[7 * 64] = a1.w;
    bs[0 * 64] = b0.x; bs[1 * 64] = b0.y; bs[2 * 64] = b0.z; bs[3 * 64] = b0.w;
    bs[4 * 64] = b1.x; bs[5 * 64] = b1.y; bs[6 * 64] = b1.z; bs[7 * 64] = b1.w;
    __syncthreads();
#pragma unroll
    for (int kk = 0; kk < 32; ++kk) {
      const float4 a = *(const float4*)&As[kk][ty << 2];
      const float4 b = *(const float4*)&Bs[kk][tx << 2];
      c[0][0] = fmaf(a.x, b.x, c[0][0]);
      c[0][1] = fmaf(a.x, b.y, c[0][1]);
      c[0][2] = fmaf(a.x, b.z, c[0][2]);
      c[0][3] = fmaf(a.x, b.w, c[0][3]);
      c[1][0] = fmaf(a.y, b.x, c[1][0]);
      c[1][1] = fmaf(a.y, b.y, c[1][1]);
      c[1][2] = fmaf(a.y, b.z, c[1][2]);
      c[1][3] = fmaf(a.y, b.w, c[1][3]);
      c[2][0] = fmaf(a.z, b.x, c[2][0]);
      c[2][1] = fmaf(a.z, b.y, c[2][1]);
      c[2][2] = fmaf(a.z, b.z, c[2][2]);
      c[2][3] = fmaf(a.z, b.w, c[2][3]);
      c[3][0] = fmaf(a.w, b.x, c[3][0]);
      c[3][1] = fmaf(a.w, b.y, c[3][1]);
      c[3][2] = fmaf(a.w, b.z, c[3][2]);
      c[3][3] = fmaf(a.w, b.w, c[3][3]);
    }
    __syncthreads();
  }
  const int head = col0 >> 6;  // col0 in 0..1023 here
  const int bb = row0 >> 11;
  const int t0 = row0 & 2047;
  unsigned short* dst = vbuf + (size_t)(bb * NH + head) * SEQ_T * DH;
#pragma unroll
  for (int i = 0; i < 4; ++i)
#pragma unroll
    for (int j = 0; j < 4; ++j) {
      __hip_bfloat16 h = __float2bfloat16(c[i][j]);
      dst[(size_t)(t0 + ty * 4 + i) * DH + (tx * 4 + j)] = *(unsigned short*)&h;
    }
}

// Attention, MFMA candidate-filter scheme (unchanged from the passing
// round-1 version).
__global__ __launch_bounds__(256) void attn_topk(
    const float* __restrict__ q, const float* __restrict__ kmat,
    const unsigned short* __restrict__ kbf,
    const unsigned short* __restrict__ v, unsigned short* __restrict__ ctx) {
  __shared__ __align__(16) unsigned short kt[128 * 64];  // 16KB swizzled tile
  __shared__ double cs64[64][CAP];                       // 16KB exact scores
  __shared__ short ckey[64][CAP];                        // 4KB candidate keys
  __shared__ int ccnt[64];
  __shared__ double rthr[64];
  __shared__ float rmx[64];

  const int tid = threadIdx.x;
  const int lane = tid & 63;
  const int w = tid >> 6;
  const int bh = blockIdx.x & 31;
  const int t0 = (blockIdx.x >> 5) << 6;
  const size_t kbase = (size_t)bh * SEQ_T * DH;
  const int wrow0 = t0 + (w << 4);
  const int kA = (lane >> 4) << 3;                 // A/B-frag k-run offset
  const int rbase = wrow0 + ((lane >> 4) << 2);    // C row of acc[0]

  // Q fragment (A operand): row = lane&15, k = 8*(lane>>4)+j (+32 for half 1)
  bf16x8v qa0, qa1;
  {
    const float* qr = q + kbase + (size_t)(wrow0 + (lane & 15)) * DH;
    const float4 x0 = *(const float4*)(qr + kA);
    const float4 x1 = *(const float4*)(qr + kA + 4);
    const float4 y0 = *(const float4*)(qr + 32 + kA);
    const float4 y1 = *(const float4*)(qr + 32 + kA + 4);
    qa0[0] = f2bs(x0.x); qa0[1] = f2bs(x0.y);
    qa0[2] = f2bs(x0.z); qa0[3] = f2bs(x0.w);
    qa0[4] = f2bs(x1.x); qa0[5] = f2bs(x1.y);
    qa0[6] = f2bs(x1.z); qa0[7] = f2bs(x1.w);
    qa1[0] = f2bs(y0.x); qa1[1] = f2bs(y0.y);
    qa1[2] = f2bs(y0.z); qa1[3] = f2bs(y0.w);
    qa1[4] = f2bs(y1.x); qa1[5] = f2bs(y1.y);
    qa1[6] = f2bs(y1.z); qa1[7] = f2bs(y1.w);
  }

  const uint4* ksrc = (const uint4*)(kbf + ((size_t)bh << 17));
  const int nt = (t0 >> 7) + 1;       // tiles covering keys 0..t0+63
  const int wmax = wrow0 + 15;

  float tq[4][8];
#pragma unroll
  for (int j = 0; j < 4; ++j)
#pragma unroll
    for (int m = 0; m < 8; ++m) tq[j][m] = -FLT_MAX;

  // ---- pass 1: MFMA scores + per-lane top-8 per slot ----
  for (int T = 0; T < nt; ++T) {
    if (T) __syncthreads();
    {
      const uint4* st = ksrc + (size_t)T * 1024;
      uint4* dv = (uint4*)kt;
#pragma unroll
      for (int i = 0; i < 4; ++i) dv[i * 256 + tid] = st[i * 256 + tid];
    }
    __syncthreads();
    const int glim0 = (wmax - (T << 7)) >> 4;
    const int glim = glim0 > 7 ? 7 : glim0;
    for (int gt = 0; gt <= glim; ++gt) {
      const int kk = (gt << 4) + (lane & 15);
      const int key = (T << 7) + kk;
      const int b0 = ((kk << 7) | (kA << 1)) ^ ((kk & 7) << 4);
      const int b1 = ((kk << 7) | ((32 + kA) << 1)) ^ ((kk & 7) << 4);
      const bf16x8v kb0 = *(const bf16x8v*)((const char*)kt + b0);
      const bf16x8v kb1 = *(const bf16x8v*)((const char*)kt + b1);
      f32x4v acc = {0.f, 0.f, 0.f, 0.f};
      acc = __builtin_amdgcn_mfma_f32_16x16x32_bf16(qa0, kb0, acc, 0, 0, 0);
      acc = __builtin_amdgcn_mfma_f32_16x16x32_bf16(qa1, kb1, acc, 0, 0, 0);
#pragma unroll
      for (int j = 0; j < 4; ++j) {
        float sc = acc[j] * 0.125f;
        sc = (key <= rbase + j) ? sc : -FLT_MAX;
        if (sc > tq[j][7]) {
          float s = sc;
#pragma unroll
          for (int m = 0; m < 8; ++m) {
            const float hi = fmaxf(tq[j][m], s);
            s = fminf(tq[j][m], s);
            tq[j][m] = hi;
          }
        }
      }
    }
  }

  // ---- merge per slot across the 16-lane group (4 bitonic rounds) ----
#pragma unroll
  for (int j = 0; j < 4; ++j) {
#pragma unroll
    for (int xm = 1; xm < 16; xm <<= 1) {
      float m[8];
#pragma unroll
      for (int i = 0; i < 8; ++i) {
        const float pb = __shfl_xor(tq[j][7 - i], xm);
        m[i] = fmaxf(tq[j][i], pb);
      }
#pragma unroll
      for (int d = 4; d >= 1; d >>= 1)
#pragma unroll
        for (int i = 0; i < 8; ++i)
          if ((i & d) == 0 && (i | d) < 8) {
            const float hi = fmaxf(m[i], m[i | d]);
            const float lo = fminf(m[i], m[i | d]);
            m[i] = hi;
            m[i | d] = lo;
          }
#pragma unroll
      for (int i = 0; i < 8; ++i) tq[j][i] = m[i];
    }
  }
  float thrj[4];
#pragma unroll
  for (int j = 0; j < 4; ++j) {
    const int kf = (rbase + j + 1 < KSEL) ? (rbase + j + 1) : KSEL;
    float th = tq[j][7];
#pragma unroll
    for (int m = 0; m < 8; ++m)
      if (m == kf - 1) th = tq[j][m];
    thrj[j] = th - MFMA_MARGIN;
  }

  if (tid < 64) ccnt[tid] = 0;
  __syncthreads();

  // ---- pass 2: identical MFMA re-scan, collect candidates ----
  for (int T = 0; T < nt; ++T) {
    if (T) __syncthreads();
    {
      const uint4* st = ksrc + (size_t)T * 1024;
      uint4* dv = (uint4*)kt;
#pragma unroll
      for (int i = 0; i < 4; ++i) dv[i * 256 + tid] = st[i * 256 + tid];
    }
    __syncthreads();
    const int glim0 = (wmax - (T << 7)) >> 4;
    const int glim = glim0 > 7 ? 7 : glim0;
    for (int gt = 0; gt <= glim; ++gt) {
      const int kk = (gt << 4) + (lane & 15);
      const int key = (T << 7) + kk;
      const int b0 = ((kk << 7) | (kA << 1)) ^ ((kk & 7) << 4);
      const int b1 = ((kk << 7) | ((32 + kA) << 1)) ^ ((kk & 7) << 4);
      const bf16x8v kb0 = *(const bf16x8v*)((const char*)kt + b0);
      const bf16x8v kb1 = *(const bf16x8v*)((const char*)kt + b1);
      f32x4v acc = {0.f, 0.f, 0.f, 0.f};
      acc = __builtin_amdgcn_mfma_f32_16x16x32_bf16(qa0, kb0, acc, 0, 0, 0);
      acc = __builtin_amdgcn_mfma_f32_16x16x32_bf16(qa1, kb1, acc, 0, 0, 0);
#pragma unroll
      for (int j = 0; j < 4; ++j) {
        const float sc = acc[j] * 0.125f;
        if (key <= rbase + j && sc >= thrj[j]) {
          const int rl = (w << 4) + ((lane >> 4) << 2) + j;
          const int p = atomicAdd(&ccnt[rl], 1);
          if (p < CAP) ckey[rl][p] = (short)key;
        }
      }
    }
  }

  // ---- phase 3A: exact fp64 rescore, lane-per-candidate, 2 rows/iter ----
  const int lid = lane & 31;
  for (int rp = 0; rp < 8; ++rp) {
    const int rl = (w << 4) + (rp << 1) + (lane >> 5);
    const int ncc = ccnt[rl] < CAP ? ccnt[rl] : CAP;
    if (lid < ncc) {
      const int key = ckey[rl][lid];
      const float* qr = q + kbase + (size_t)(t0 + rl) * DH;
      const float* kr = kmat + kbase + (size_t)key * DH;
      double s = 0.0;
#pragma unroll
      for (int d4 = 0; d4 < 16; ++d4) {
        const float4 qq = *(const float4*)(qr + (d4 << 2));
        const float4 kq = *(const float4*)(kr + (d4 << 2));
        s = fma((double)qq.x, (double)kq.x, s);
        s = fma((double)qq.y, (double)kq.y, s);
        s = fma((double)qq.z, (double)kq.z, s);
        s = fma((double)qq.w, (double)kq.w, s);
      }
      cs64[rl][lid] = s * 0.125;
    }
  }
  __syncthreads();

  // ---- phase 3B: per-row fp64 top-8 + threshold (row per lane) ----
  if (lane < 16) {
    const int rl = (w << 4) + lane;
    const int trow = t0 + rl;
    const int ncc = ccnt[rl] < CAP ? ccnt[rl] : CAP;
    double a64[8];
#pragma unroll
    for (int j = 0; j < 8; ++j) a64[j] = -DBL_MAX;
    for (int l = 0; l < ncc; ++l) {
      double sv = cs64[rl][l];
#pragma unroll
      for (int j = 0; j < 8; ++j) {
        const double hi = fmax(a64[j], sv);
        sv = fmin(a64[j], sv);
        a64[j] = hi;
      }
    }
    const int kf = (trow + 1 < KSEL) ? (trow + 1) : KSEL;
    double th = a64[7];
#pragma unroll
    for (int j = 0; j < 8; ++j)
      if (j == kf - 1) th = a64[j];
    rthr[rl] = th;
    rmx[rl] = (float)a64[0];
  }
  __syncthreads();

  // ---- phase 3C: sparse softmax * V (keep = s64 >= thr64, ties kept) ----
  for (int r = 0; r < 16; ++r) {
    const int rl = (w << 4) + r;
    const int ncc = ccnt[rl] < CAP ? ccnt[rl] : CAP;
    const double th = rthr[rl];
    const float mxf = rmx[rl];
    float accv = 0.f, Z = 0.f;
    for (int l = 0; l < ncc; ++l) {
      const double s = cs64[rl][l];
      if (s >= th) {
        const float wg = expf((float)s - mxf);
        Z += wg;
        accv = fmaf(
            wg,
            bf2f((unsigned int)v[kbase + (size_t)ckey[rl][l] * DH + lane]),
            accv);
      }
    }
    const int trow = t0 + rl;
    __hip_bfloat16 h = __float2bfloat16(accv / Z);
    ctx[((size_t)(bh >> 4) * SEQ_T + trow) * DIM_D + (bh & 15) * DH + lane] =
        *(unsigned short*)&h;
  }
}

// Output projection: out[4096 x 1024] = ctx(bf16) * wout^T(fp32), fp32 out.
__global__ __launch_bounds__(256) void gemm_out(
    const unsigned short* __restrict__ A, const float* __restrict__ Bm,
    float* __restrict__ obuf) {
  __shared__ __align__(16) float As[32][64];
  __shared__ __align__(16) float Bs[32][64];
  const int tid = threadIdx.x;
  const int row0 = blockIdx.y * 64;
  const int col0 = blockIdx.x * 64;
  const int lrow = tid >> 2;
  const int lk = (tid & 3) << 3;
  const int tx = tid & 15, ty = tid >> 4;
  const unsigned short* ap = A + (size_t)(row0 + lrow) * KDIM + lk;
  const float* bp = Bm + (size_t)(col0 + lrow) * KDIM + lk;
  float c[4][4] = {{0.f, 0.f, 0.f, 0.f}};
  for (int k0 = 0; k0 < KDIM; k0 += 32) {
    const uint4 u = *(const uint4*)(ap + k0);
    const float4 b0 = *(const float4*)(bp + k0);
    const float4 b1 = *(const float4*)(bp + k0 + 4);
    float* as = &As[lk][lrow];
    float* bs = &Bs[lk][lrow];
    as[0 * 64] = bf2f(u.x & 0xffffu); as[1 * 64] = bf2f(u.x >> 16);
    as[2 * 64] = bf2f(u.y & 0xffffu); as[3 * 64] = bf2f(u.y >> 16);
    as[4 * 64] = bf2f(u.z & 0xffffu); as[5 * 64] = bf2f(u.z >> 16);
    as[6 * 64] = bf2f(u.w & 0xffffu); as[7 * 64] = bf2f(u.w >> 16);
    bs[0 * 64] = b0.x; bs[1 * 64] = b0.y; bs[2 * 64] = b0.z; bs[3 * 64] = b0.w;
    bs[4 * 64] = b1.x; bs[5 * 64] = b1.y; bs[6 * 64] = b1.z; bs[7 * 64] = b1.w;
    __syncthreads();
#pragma unroll
    for (int kk = 0; kk < 32; ++kk) {
      const float4 a = *(const float4*)&As[kk][ty << 2];
      const float4 b = *(const float4*)&Bs[kk][tx << 2];
      c[0][0] = fmaf(a.x, b.x, c[0][0]);
      c[0][1] = fmaf(a.x, b.y, c[0][1]);
      c[0][2] = fmaf(a.x, b.z, c[0][2]);
      c[0][3] = fmaf(a.x, b.w, c[0][3]);
      c[1][0] = fmaf(a.y, b.x, c[1][0]);
      c[1][1] = fmaf(a.y, b.y, c[1][1]);
      c[1][2] = fmaf(a.y, b.z, c[1][2]);
      c[1][3] = fmaf(a.y, b.w, c[1][3]);
      c[2][0] = fmaf(a.z, b.x, c[2][0]);
      c[2][1] = fmaf(a.z, b.y, c[2][1]);
      c[2][2] = fmaf(a.z, b.z, c[2][2]);
      c[2][3] = fmaf(a.z, b.w, c[2][3]);
      c[3][0] = fmaf(a.w, b.x, c[3][0]);
      c[3][1] = fmaf(a.w, b.y, c[3][1]);
      c[3][2] = fmaf(a.w, b.z, c[3][2]);
      c[3][3] = fmaf(a.w, b.w, c[3][3]);
    }
    __syncthreads();
  }
#pragma unroll
  for (int i = 0; i < 4; ++i)
#pragma unroll
    for (int j = 0; j < 4; ++j)
      obuf[(size_t)(row0 + ty * 4 + i) * DIM_D + (col0 + tx * 4 + j)] = c[i][j];
}

extern "C" void kernel_launch(void* const* d_in, const int* in_sizes, int n_in,
                              void* d_out, int out_size, void* d_ws,
                              size_t ws_size, hipStream_t stream) {
  (void)out_size; (void)ws_size;
  const float* x = (const float*)d_in[0];
  const float* wqkv = (const float*)d_in[1];
  const float* wout = (const float*)d_in[2];
  for (int i = 0; i < n_in; ++i) {
    if (in_sizes[i] == NUM_B * SEQ_T * DIM_D) x = (const float*)d_in[i];
    else if (in_sizes[i] == 3 * DIM_D * DIM_D) wqkv = (const float*)d_in[i];
    else if (in_sizes[i] == DIM_D * DIM_D) wout = (const float*)d_in[i];
  }
  float* out = (float*)d_out;

  const size_t qkv_elems = (size_t)NUM_B * NH * SEQ_T * DH;   // 4.19M
  float* qbuf = (float*)d_ws;
  float* kbuf = qbuf + qkv_elems;
  unsigned short* vbuf = (unsigned short*)(kbuf + qkv_elems);
  unsigned short* ctxb = vbuf + qkv_elems;
  unsigned short* kbf = ctxb + (size_t)NUM_B * SEQ_T * DIM_D;  // bf16 K tiles

  gemm_qk<<<dim3(2 * DIM_D / 64, NUM_B * SEQ_T / 64), 256, 0, stream>>>(
      x, wqkv, qbuf, kbuf, kbf);
  gemm_v<<<dim3(DIM_D / 64, NUM_B * SEQ_T / 64), 256, 0, stream>>>(
      x, wqkv + (size_t)2 * DIM_D * KDIM, vbuf);
  attn_topk<<<dim3(NUM_B * NH * (SEQ_T / 64)), 256, 0, stream>>>(
      qbuf, kbuf, kbf, vbuf, ctxb);
  gemm_out<<<dim3(DIM_D / 64, NUM_B * SEQ_T / 64), 256, 0, stream>>>(
      ctxb, wout, out);
}

// Round 4
// 629.524 us; speedup vs baseline: 1.9258x; 1.2555x over previous
//
#include <hip/hip_runtime.h>
#include <hip/hip_bf16.h>
#include <math.h>
#include <float.h>

#define NUM_B 2
#define SEQ_T 2048
#define DIM_D 1024
#define NH 16
#define DH 64
#define KDIM 1024
#define KSEL 8

// attention candidate scheme
#define CAP 32
#define MFMA_MARGIN 0.06f

typedef __attribute__((ext_vector_type(8))) short bf16x8v;   // 8 bf16 (4 VGPR)
typedef __attribute__((ext_vector_type(4))) float f32x4v;    // MFMA acc
typedef __attribute__((ext_vector_type(4))) double f64x4v;   // f64 MFMA acc

__device__ __forceinline__ float bf2f(unsigned int u) {
  union { unsigned int i; float f; } v; v.i = u << 16; return v.f;
}

__device__ __forceinline__ short f2bs(float f) {
  __hip_bfloat16 h = __float2bfloat16(f);
  return *(short*)&h;
}

// split x into hi+lo bf16 (residual ~1.6e-5 rel); store 8 to LDS as 16B each
__device__ __forceinline__ void split8(float4 x0, float4 x1,
                                       unsigned short* __restrict__ hp,
                                       unsigned short* __restrict__ lp) {
  unsigned short h[8], l[8];
  const float xs[8] = {x0.x, x0.y, x0.z, x0.w, x1.x, x1.y, x1.z, x1.w};
#pragma unroll
  for (int j = 0; j < 8; ++j) {
    const short hb = f2bs(xs[j]);
    h[j] = (unsigned short)hb;
    const float hf = bf2f((unsigned int)(unsigned short)hb);
    l[j] = (unsigned short)f2bs(xs[j] - hf);
  }
  *(uint4*)hp = *(const uint4*)h;
  *(uint4*)lp = *(const uint4*)l;
}

// Q,K projection (cols 0..2047 of qkv): fp64 accumulation via
// v_mfma_f64_16x16x4 (matrix pipe). MFMA order identical to the round-3
// passing version (bit-exact Q/K); global loads are software-pipelined one
// K-chunk ahead so the load stall hides under the 32-MFMA compute phase.
// C/D layout decoded at runtime with two probe MFMAs (round-2 lesson).
// Also emits kbf: bf16 K image, XOR-swizzled for attn's linear LDS staging.
__global__ __launch_bounds__(256) void gemm_qk(
    const float* __restrict__ A, const float* __restrict__ Bm,
    float* __restrict__ qbuf, float* __restrict__ kbuf,
    unsigned short* __restrict__ kbf) {
  __shared__ __align__(16) float As[64][36];   // row-major, +4 pad
  __shared__ __align__(16) float Bs[64][36];
  const int tid = threadIdx.x;
  const int lane = tid & 63;
  const int w = tid >> 6;
  const int row0 = blockIdx.y * 64;
  const int col0 = blockIdx.x * 64;
  const int lrow = tid >> 2;        // 0..63
  const int lk = (tid & 3) << 3;    // 0,8,16,24
  const float* ap = A + (size_t)(row0 + lrow) * KDIM + lk;
  const float* bp = Bm + (size_t)(col0 + lrow) * KDIM + lk;
  const int wr = (w >> 1) << 5;     // 0 or 32 (row offset)
  const int wc = (w & 1) << 5;      // 0 or 32 (col offset)
  const int li = lane & 15;         // A row / B col within subtile
  const int lk4 = lane >> 4;        // k within 4-step (A/B frag)

  // ---- C/D layout probe: decode (row,col) of each acc slot at runtime ----
  int rowof[4], colof[4];
  {
    f64x4v pr = {0.0, 0.0, 0.0, 0.0};
    f64x4v pc = {0.0, 0.0, 0.0, 0.0};
    const double vidx = (double)li;
    pr = __builtin_amdgcn_mfma_f64_16x16x4f64(vidx, 1.0, pr, 0, 0, 0);
    pc = __builtin_amdgcn_mfma_f64_16x16x4f64(1.0, vidx, pc, 0, 0, 0);
#pragma unroll
    for (int vj = 0; vj < 4; ++vj) {
      rowof[vj] = (int)(pr[vj] * 0.25 + 0.5);
      colof[vj] = (int)(pc[vj] * 0.25 + 0.5);
    }
  }

  f64x4v acc[2][2];
#pragma unroll
  for (int m = 0; m < 2; ++m)
#pragma unroll
    for (int n = 0; n < 2; ++n)
      acc[m][n] = (f64x4v){0.0, 0.0, 0.0, 0.0};

  // software-pipelined staging: loads for chunk c+1 issue before chunk c's
  // MFMA phase, so latency hides under ~32 f64 MFMAs.
  float4 ra0 = *(const float4*)(ap);
  float4 ra1 = *(const float4*)(ap + 4);
  float4 rb0 = *(const float4*)(bp);
  float4 rb1 = *(const float4*)(bp + 4);
  for (int k0 = 0; k0 < KDIM; k0 += 32) {
    __syncthreads();   // previous chunk's readers done
    *(float4*)&As[lrow][lk] = ra0;
    *(float4*)&As[lrow][lk + 4] = ra1;
    *(float4*)&Bs[lrow][lk] = rb0;
    *(float4*)&Bs[lrow][lk + 4] = rb1;
    if (k0 + 32 < KDIM) {
      ra0 = *(const float4*)(ap + k0 + 32);
      ra1 = *(const float4*)(ap + k0 + 36);
      rb0 = *(const float4*)(bp + k0 + 32);
      rb1 = *(const float4*)(bp + k0 + 36);
    }
    __syncthreads();
#pragma unroll
    for (int ks = 0; ks < 32; ks += 4) {
      const int kk = ks + lk4;
      const double af0 = (double)As[wr + li][kk];
      const double af1 = (double)As[wr + 16 + li][kk];
      const double bf0 = (double)Bs[wc + li][kk];
      const double bf1 = (double)Bs[wc + 16 + li][kk];
      acc[0][0] = __builtin_amdgcn_mfma_f64_16x16x4f64(af0, bf0, acc[0][0], 0, 0, 0);
      acc[0][1] = __builtin_amdgcn_mfma_f64_16x16x4f64(af0, bf1, acc[0][1], 0, 0, 0);
      acc[1][0] = __builtin_amdgcn_mfma_f64_16x16x4f64(af1, bf0, acc[1][0], 0, 0, 0);
      acc[1][1] = __builtin_amdgcn_mfma_f64_16x16x4f64(af1, bf1, acc[1][1], 0, 0, 0);
    }
  }

  const int qi = col0 >> 10;            // 0=q 1=k
  const int head = (col0 & 1023) >> 6;
  const int bb = row0 >> 11;
  const int t0 = row0 & 2047;
  const size_t base = (size_t)(bb * NH + head) * SEQ_T * DH;
  float* dst = ((qi == 0) ? qbuf : kbuf) + base;
  unsigned short* kb = kbf + ((size_t)(bb * NH + head) << 17);  // 16*8192
#pragma unroll
  for (int m = 0; m < 2; ++m)
#pragma unroll
    for (int n = 0; n < 2; ++n)
#pragma unroll
      for (int vj = 0; vj < 4; ++vj) {
        const int r = wr + 16 * m + rowof[vj];      // row in tile (0..63)
        const int dcol = wc + 16 * n + colof[vj];   // col in tile (0..63)
        const int t = t0 + r;
        const float fv = (float)acc[m][n][vj];
        dst[(size_t)t * DH + dcol] = fv;
        if (qi == 1) {
          const int key = t & 127;
          const int off =
              (((t >> 7) << 13) | (key << 6) | dcol) ^ ((key & 7) << 3);
          __hip_bfloat16 hb = __float2bfloat16(fv);
          kb[off] = *(unsigned short*)&hb;
        }
      }
}

// V projection (cols 2048..3071): split-bf16 MFMA. x = hi+lo bf16;
// C = Ah*Bh + Ah*Bl + Al*Bh in fp32 MFMA accumulators (dropped lo*lo term
// ~1.6e-5 rel — invisible at V's bf16 granularity, ulp 4e-3).
// Bm passed pre-offset to wqkv + 2048*KDIM.
__global__ __launch_bounds__(256) void gemm_v(
    const float* __restrict__ A, const float* __restrict__ Bm,
    unsigned short* __restrict__ vbuf) {
  __shared__ __align__(16) unsigned short Ah[64][40];  // rows padded to 80B
  __shared__ __align__(16) unsigned short Al[64][40];
  __shared__ __align__(16) unsigned short Bh[64][40];
  __shared__ __align__(16) unsigned short Bl[64][40];
  const int tid = threadIdx.x;
  const int lane = tid & 63;
  const int w = tid >> 6;
  const int row0 = blockIdx.y * 64;
  const int col0 = blockIdx.x * 64;
  const int lrow = tid >> 2;
  const int lk = (tid & 3) << 3;
  const float* ap = A + (size_t)(row0 + lrow) * KDIM + lk;
  const float* bp = Bm + (size_t)(col0 + lrow) * KDIM + lk;
  const int wr = (w >> 1) << 5;
  const int wc = (w & 1) << 5;
  const int li = lane & 15;
  const int kA = (lane >> 4) << 3;   // frag k-run: k = kA + j (verified map)

  f32x4v acc[2][2];
#pragma unroll
  for (int m = 0; m < 2; ++m)
#pragma unroll
    for (int n = 0; n < 2; ++n)
      acc[m][n] = (f32x4v){0.f, 0.f, 0.f, 0.f};

  float4 ra0 = *(const float4*)(ap);
  float4 ra1 = *(const float4*)(ap + 4);
  float4 rb0 = *(const float4*)(bp);
  float4 rb1 = *(const float4*)(bp + 4);
  for (int k0 = 0; k0 < KDIM; k0 += 32) {
    __syncthreads();
    split8(ra0, ra1, &Ah[lrow][lk], &Al[lrow][lk]);
    split8(rb0, rb1, &Bh[lrow][lk], &Bl[lrow][lk]);
    if (k0 + 32 < KDIM) {
      ra0 = *(const float4*)(ap + k0 + 32);
      ra1 = *(const float4*)(ap + k0 + 36);
      rb0 = *(const float4*)(bp + k0 + 32);
      rb1 = *(const float4*)(bp + k0 + 36);
    }
    __syncthreads();
    bf16x8v ah[2], al[2], bh[2], bl[2];
#pragma unroll
    for (int m = 0; m < 2; ++m) {
      ah[m] = *(const bf16x8v*)&Ah[wr + 16 * m + li][kA];
      al[m] = *(const bf16x8v*)&Al[wr + 16 * m + li][kA];
      bh[m] = *(const bf16x8v*)&Bh[wc + 16 * m + li][kA];
      bl[m] = *(const bf16x8v*)&Bl[wc + 16 * m + li][kA];
    }
#pragma unroll
    for (int m = 0; m < 2; ++m)
#pragma unroll
      for (int n = 0; n < 2; ++n) {
        acc[m][n] = __builtin_amdgcn_mfma_f32_16x16x32_bf16(ah[m], bh[n], acc[m][n], 0, 0, 0);
        acc[m][n] = __builtin_amdgcn_mfma_f32_16x16x32_bf16(ah[m], bl[n], acc[m][n], 0, 0, 0);
        acc[m][n] = __builtin_amdgcn_mfma_f32_16x16x32_bf16(al[m], bh[n], acc[m][n], 0, 0, 0);
      }
  }

  const int head = col0 >> 6;  // col0 in 0..1023 here; tile within one head
  const int bb = row0 >> 11;
  const int t0 = row0 & 2047;
  unsigned short* dst = vbuf + (size_t)(bb * NH + head) * SEQ_T * DH;
  const int r4 = (lane >> 4) << 2;  // C row base (verified bf16 C layout)
#pragma unroll
  for (int m = 0; m < 2; ++m)
#pragma unroll
    for (int n = 0; n < 2; ++n)
#pragma unroll
      for (int j = 0; j < 4; ++j) {
        const int t = t0 + wr + 16 * m + r4 + j;
        const int d = wc + 16 * n + li;
        dst[(size_t)t * DH + d] = (unsigned short)f2bs(acc[m][n][j]);
      }
}

// Attention, MFMA candidate-filter scheme (unchanged from the passing
// round-1 version).
__global__ __launch_bounds__(256) void attn_topk(
    const float* __restrict__ q, const float* __restrict__ kmat,
    const unsigned short* __restrict__ kbf,
    const unsigned short* __restrict__ v, unsigned short* __restrict__ ctx) {
  __shared__ __align__(16) unsigned short kt[128 * 64];  // 16KB swizzled tile
  __shared__ double cs64[64][CAP];                       // 16KB exact scores
  __shared__ short ckey[64][CAP];                        // 4KB candidate keys
  __shared__ int ccnt[64];
  __shared__ double rthr[64];
  __shared__ float rmx[64];

  const int tid = threadIdx.x;
  const int lane = tid & 63;
  const int w = tid >> 6;
  const int bh = blockIdx.x & 31;
  const int t0 = (blockIdx.x >> 5) << 6;
  const size_t kbase = (size_t)bh * SEQ_T * DH;
  const int wrow0 = t0 + (w << 4);
  const int kA = (lane >> 4) << 3;                 // A/B-frag k-run offset
  const int rbase = wrow0 + ((lane >> 4) << 2);    // C row of acc[0]

  // Q fragment (A operand): row = lane&15, k = 8*(lane>>4)+j (+32 for half 1)
  bf16x8v qa0, qa1;
  {
    const float* qr = q + kbase + (size_t)(wrow0 + (lane & 15)) * DH;
    const float4 x0 = *(const float4*)(qr + kA);
    const float4 x1 = *(const float4*)(qr + kA + 4);
    const float4 y0 = *(const float4*)(qr + 32 + kA);
    const float4 y1 = *(const float4*)(qr + 32 + kA + 4);
    qa0[0] = f2bs(x0.x); qa0[1] = f2bs(x0.y);
    qa0[2] = f2bs(x0.z); qa0[3] = f2bs(x0.w);
    qa0[4] = f2bs(x1.x); qa0[5] = f2bs(x1.y);
    qa0[6] = f2bs(x1.z); qa0[7] = f2bs(x1.w);
    qa1[0] = f2bs(y0.x); qa1[1] = f2bs(y0.y);
    qa1[2] = f2bs(y0.z); qa1[3] = f2bs(y0.w);
    qa1[4] = f2bs(y1.x); qa1[5] = f2bs(y1.y);
    qa1[6] = f2bs(y1.z); qa1[7] = f2bs(y1.w);
  }

  const uint4* ksrc = (const uint4*)(kbf + ((size_t)bh << 17));
  const int nt = (t0 >> 7) + 1;       // tiles covering keys 0..t0+63
  const int wmax = wrow0 + 15;

  float tq[4][8];
#pragma unroll
  for (int j = 0; j < 4; ++j)
#pragma unroll
    for (int m = 0; m < 8; ++m) tq[j][m] = -FLT_MAX;

  // ---- pass 1: MFMA scores + per-lane top-8 per slot ----
  for (int T = 0; T < nt; ++T) {
    if (T) __syncthreads();
    {
      const uint4* st = ksrc + (size_t)T * 1024;
      uint4* dv = (uint4*)kt;
#pragma unroll
      for (int i = 0; i < 4; ++i) dv[i * 256 + tid] = st[i * 256 + tid];
    }
    __syncthreads();
    const int glim0 = (wmax - (T << 7)) >> 4;
    const int glim = glim0 > 7 ? 7 : glim0;
    for (int gt = 0; gt <= glim; ++gt) {
      const int kk = (gt << 4) + (lane & 15);
      const int key = (T << 7) + kk;
      const int b0 = ((kk << 7) | (kA << 1)) ^ ((kk & 7) << 4);
      const int b1 = ((kk << 7) | ((32 + kA) << 1)) ^ ((kk & 7) << 4);
      const bf16x8v kb0 = *(const bf16x8v*)((const char*)kt + b0);
      const bf16x8v kb1 = *(const bf16x8v*)((const char*)kt + b1);
      f32x4v acc = {0.f, 0.f, 0.f, 0.f};
      acc = __builtin_amdgcn_mfma_f32_16x16x32_bf16(qa0, kb0, acc, 0, 0, 0);
      acc = __builtin_amdgcn_mfma_f32_16x16x32_bf16(qa1, kb1, acc, 0, 0, 0);
#pragma unroll
      for (int j = 0; j < 4; ++j) {
        float sc = acc[j] * 0.125f;
        sc = (key <= rbase + j) ? sc : -FLT_MAX;
        if (sc > tq[j][7]) {
          float s = sc;
#pragma unroll
          for (int m = 0; m < 8; ++m) {
            const float hi = fmaxf(tq[j][m], s);
            s = fminf(tq[j][m], s);
            tq[j][m] = hi;
          }
        }
      }
    }
  }

  // ---- merge per slot across the 16-lane group (4 bitonic rounds) ----
#pragma unroll
  for (int j = 0; j < 4; ++j) {
#pragma unroll
    for (int xm = 1; xm < 16; xm <<= 1) {
      float m[8];
#pragma unroll
      for (int i = 0; i < 8; ++i) {
        const float pb = __shfl_xor(tq[j][7 - i], xm);
        m[i] = fmaxf(tq[j][i], pb);
      }
#pragma unroll
      for (int d = 4; d >= 1; d >>= 1)
#pragma unroll
        for (int i = 0; i < 8; ++i)
          if ((i & d) == 0 && (i | d) < 8) {
            const float hi = fmaxf(m[i], m[i | d]);
            const float lo = fminf(m[i], m[i | d]);
            m[i] = hi;
            m[i | d] = lo;
          }
#pragma unroll
      for (int i = 0; i < 8; ++i) tq[j][i] = m[i];
    }
  }
  float thrj[4];
#pragma unroll
  for (int j = 0; j < 4; ++j) {
    const int kf = (rbase + j + 1 < KSEL) ? (rbase + j + 1) : KSEL;
    float th = tq[j][7];
#pragma unroll
    for (int m = 0; m < 8; ++m)
      if (m == kf - 1) th = tq[j][m];
    thrj[j] = th - MFMA_MARGIN;
  }

  if (tid < 64) ccnt[tid] = 0;
  __syncthreads();

  // ---- pass 2: identical MFMA re-scan, collect candidates ----
  for (int T = 0; T < nt; ++T) {
    if (T) __syncthreads();
    {
      const uint4* st = ksrc + (size_t)T * 1024;
      uint4* dv = (uint4*)kt;
#pragma unroll
      for (int i = 0; i < 4; ++i) dv[i * 256 + tid] = st[i * 256 + tid];
    }
    __syncthreads();
    const int glim0 = (wmax - (T << 7)) >> 4;
    const int glim = glim0 > 7 ? 7 : glim0;
    for (int gt = 0; gt <= glim; ++gt) {
      const int kk = (gt << 4) + (lane & 15);
      const int key = (T << 7) + kk;
      const int b0 = ((kk << 7) | (kA << 1)) ^ ((kk & 7) << 4);
      const int b1 = ((kk << 7) | ((32 + kA) << 1)) ^ ((kk & 7) << 4);
      const bf16x8v kb0 = *(const bf16x8v*)((const char*)kt + b0);
      const bf16x8v kb1 = *(const bf16x8v*)((const char*)kt + b1);
      f32x4v acc = {0.f, 0.f, 0.f, 0.f};
      acc = __builtin_amdgcn_mfma_f32_16x16x32_bf16(qa0, kb0, acc, 0, 0, 0);
      acc = __builtin_amdgcn_mfma_f32_16x16x32_bf16(qa1, kb1, acc, 0, 0, 0);
#pragma unroll
      for (int j = 0; j < 4; ++j) {
        const float sc = acc[j] * 0.125f;
        if (key <= rbase + j && sc >= thrj[j]) {
          const int rl = (w << 4) + ((lane >> 4) << 2) + j;
          const int p = atomicAdd(&ccnt[rl], 1);
          if (p < CAP) ckey[rl][p] = (short)key;
        }
      }
    }
  }

  // ---- phase 3A: exact fp64 rescore, lane-per-candidate, 2 rows/iter ----
  const int lid = lane & 31;
  for (int rp = 0; rp < 8; ++rp) {
    const int rl = (w << 4) + (rp << 1) + (lane >> 5);
    const int ncc = ccnt[rl] < CAP ? ccnt[rl] : CAP;
    if (lid < ncc) {
      const int key = ckey[rl][lid];
      const float* qr = q + kbase + (size_t)(t0 + rl) * DH;
      const float* kr = kmat + kbase + (size_t)key * DH;
      double s = 0.0;
#pragma unroll
      for (int d4 = 0; d4 < 16; ++d4) {
        const float4 qq = *(const float4*)(qr + (d4 << 2));
        const float4 kq = *(const float4*)(kr + (d4 << 2));
        s = fma((double)qq.x, (double)kq.x, s);
        s = fma((double)qq.y, (double)kq.y, s);
        s = fma((double)qq.z, (double)kq.z, s);
        s = fma((double)qq.w, (double)kq.w, s);
      }
      cs64[rl][lid] = s * 0.125;
    }
  }
  __syncthreads();

  // ---- phase 3B: per-row fp64 top-8 + threshold (row per lane) ----
  if (lane < 16) {
    const int rl = (w << 4) + lane;
    const int trow = t0 + rl;
    const int ncc = ccnt[rl] < CAP ? ccnt[rl] : CAP;
    double a64[8];
#pragma unroll
    for (int j = 0; j < 8; ++j) a64[j] = -DBL_MAX;
    for (int l = 0; l < ncc; ++l) {
      double sv = cs64[rl][l];
#pragma unroll
      for (int j = 0; j < 8; ++j) {
        const double hi = fmax(a64[j], sv);
        sv = fmin(a64[j], sv);
        a64[j] = hi;
      }
    }
    const int kf = (trow + 1 < KSEL) ? (trow + 1) : KSEL;
    double th = a64[7];
#pragma unroll
    for (int j = 0; j < 8; ++j)
      if (j == kf - 1) th = a64[j];
    rthr[rl] = th;
    rmx[rl] = (float)a64[0];
  }
  __syncthreads();

  // ---- phase 3C: sparse softmax * V (keep = s64 >= thr64, ties kept) ----
  for (int r = 0; r < 16; ++r) {
    const int rl = (w << 4) + r;
    const int ncc = ccnt[rl] < CAP ? ccnt[rl] : CAP;
    const double th = rthr[rl];
    const float mxf = rmx[rl];
    float accv = 0.f, Z = 0.f;
    for (int l = 0; l < ncc; ++l) {
      const double s = cs64[rl][l];
      if (s >= th) {
        const float wg = expf((float)s - mxf);
        Z += wg;
        accv = fmaf(
            wg,
            bf2f((unsigned int)v[kbase + (size_t)ckey[rl][l] * DH + lane]),
            accv);
      }
    }
    const int trow = t0 + rl;
    __hip_bfloat16 h = __float2bfloat16(accv / Z);
    ctx[((size_t)(bh >> 4) * SEQ_T + trow) * DIM_D + (bh & 15) * DH + lane] =
        *(unsigned short*)&h;
  }
}

// Output projection via MFMA: A = ctx (exactly bf16), B = wout split to
// hi+lo bf16; C = A*Bh + A*Bl in fp32 accumulators (~1.6e-5 rel error vs
// fp32 chain — output threshold is 0.0765).
__global__ __launch_bounds__(256) void gemm_out(
    const unsigned short* __restrict__ A, const float* __restrict__ Bm,
    float* __restrict__ obuf) {
  __shared__ __align__(16) unsigned short Ah[64][40];
  __shared__ __align__(16) unsigned short Bh[64][40];
  __shared__ __align__(16) unsigned short Bl[64][40];
  const int tid = threadIdx.x;
  const int lane = tid & 63;
  const int w = tid >> 6;
  const int row0 = blockIdx.y * 64;
  const int col0 = blockIdx.x * 64;
  const int lrow = tid >> 2;
  const int lk = (tid & 3) << 3;
  const unsigned short* ap = A + (size_t)(row0 + lrow) * KDIM + lk;
  const float* bp = Bm + (size_t)(col0 + lrow) * KDIM + lk;
  const int wr = (w >> 1) << 5;
  const int wc = (w & 1) << 5;
  const int li = lane & 15;
  const int kA = (lane >> 4) << 3;

  f32x4v acc[2][2];
#pragma unroll
  for (int m = 0; m < 2; ++m)
#pragma unroll
    for (int n = 0; n < 2; ++n)
      acc[m][n] = (f32x4v){0.f, 0.f, 0.f, 0.f};

  uint4 ua = *(const uint4*)(ap);
  float4 rb0 = *(const float4*)(bp);
  float4 rb1 = *(const float4*)(bp + 4);
  for (int k0 = 0; k0 < KDIM; k0 += 32) {
    __syncthreads();
    *(uint4*)&Ah[lrow][lk] = ua;
    split8(rb0, rb1, &Bh[lrow][lk], &Bl[lrow][lk]);
    if (k0 + 32 < KDIM) {
      ua = *(const uint4*)(ap + k0 + 32);
      rb0 = *(const float4*)(bp + k0 + 32);
      rb1 = *(const float4*)(bp + k0 + 36);
    }
    __syncthreads();
    bf16x8v ah[2], bh[2], bl[2];
#pragma unroll
    for (int m = 0; m < 2; ++m) {
      ah[m] = *(const bf16x8v*)&Ah[wr + 16 * m + li][kA];
      bh[m] = *(const bf16x8v*)&Bh[wc + 16 * m + li][kA];
      bl[m] = *(const bf16x8v*)&Bl[wc + 16 * m + li][kA];
    }
#pragma unroll
    for (int m = 0; m < 2; ++m)
#pragma unroll
      for (int n = 0; n < 2; ++n) {
        acc[m][n] = __builtin_amdgcn_mfma_f32_16x16x32_bf16(ah[m], bh[n], acc[m][n], 0, 0, 0);
        acc[m][n] = __builtin_amdgcn_mfma_f32_16x16x32_bf16(ah[m], bl[n], acc[m][n], 0, 0, 0);
      }
  }

  const int r4 = (lane >> 4) << 2;
#pragma unroll
  for (int m = 0; m < 2; ++m)
#pragma unroll
    for (int n = 0; n < 2; ++n)
#pragma unroll
      for (int j = 0; j < 4; ++j) {
        const int r = row0 + wr + 16 * m + r4 + j;
        const int c = col0 + wc + 16 * n + li;
        obuf[(size_t)r * DIM_D + c] = acc[m][n][j];
      }
}

extern "C" void kernel_launch(void* const* d_in, const int* in_sizes, int n_in,
                              void* d_out, int out_size, void* d_ws,
                              size_t ws_size, hipStream_t stream) {
  (void)out_size; (void)ws_size;
  const float* x = (const float*)d_in[0];
  const float* wqkv = (const float*)d_in[1];
  const float* wout = (const float*)d_in[2];
  for (int i = 0; i < n_in; ++i) {
    if (in_sizes[i] == NUM_B * SEQ_T * DIM_D) x = (const float*)d_in[i];
    else if (in_sizes[i] == 3 * DIM_D * DIM_D) wqkv = (const float*)d_in[i];
    else if (in_sizes[i] == DIM_D * DIM_D) wout = (const float*)d_in[i];
  }
  float* out = (float*)d_out;

  const size_t qkv_elems = (size_t)NUM_B * NH * SEQ_T * DH;   // 4.19M
  float* qbuf = (float*)d_ws;
  float* kbuf = qbuf + qkv_elems;
  unsigned short* vbuf = (unsigned short*)(kbuf + qkv_elems);
  unsigned short* ctxb = vbuf + qkv_elems;
  unsigned short* kbf = ctxb + (size_t)NUM_B * SEQ_T * DIM_D;  // bf16 K tiles

  gemm_qk<<<dim3(2 * DIM_D / 64, NUM_B * SEQ_T / 64), 256, 0, stream>>>(
      x, wqkv, qbuf, kbuf, kbf);
  gemm_v<<<dim3(DIM_D / 64, NUM_B * SEQ_T / 64), 256, 0, stream>>>(
      x, wqkv + (size_t)2 * DIM_D * KDIM, vbuf);
  attn_topk<<<dim3(NUM_B * NH * (SEQ_T / 64)), 256, 0, stream>>>(
      qbuf, kbuf, kbf, vbuf, ctxb);
  gemm_out<<<dim3(DIM_D / 64, NUM_B * SEQ_T / 64), 256, 0, stream>>>(
      ctxb, wout, out);
}